// Round 1
// baseline (190.551 us; speedup 1.0000x reference)
//
#include <hip/hip_runtime.h>

// Instant-NGP hash-grid trilinear interpolation.
// pts: (N,3) f32 in [0,1)^3; voxel_features: (buckets, 8) f32; out: (N, 8) f32.
// Per point: q = p/0.005 (f32 divide, must match XLA's rounding so floor()
// agrees at cell boundaries), 8 corner hashes (x*1 ^ y*2654435761 ^ z*805459861
// mod buckets), gather 8x 32B feature rows, trilinear-weighted sum.

__global__ __launch_bounds__(256) void ngp_hash_interp(
    const float* __restrict__ pts,
    const float* __restrict__ feat,
    float* __restrict__ out,
    int N, unsigned buckets, int is_pow2)
{
    int i = blockIdx.x * blockDim.x + threadIdx.x;
    if (i >= N) return;

    float px = pts[3 * i + 0];
    float py = pts[3 * i + 1];
    float pz = pts[3 * i + 2];

    // f32 divide by the float closest to 0.005 — matches jnp pts / RES.
    float qx = px / 0.005f;
    float qy = py / 0.005f;
    float qz = pz / 0.005f;

    float bx = floorf(qx), by = floorf(qy), bz = floorf(qz);
    float fx = qx - bx, fy = qy - by, fz = qz - bz;

    // pts in [0,1) -> base in [0,199]; no negatives.
    unsigned ux = (unsigned)(int)bx;
    unsigned uy = (unsigned)(int)by;
    unsigned uz = (unsigned)(int)bz;

    unsigned hx0 = ux;                          // * PRIMES[0] == 1
    unsigned hx1 = ux + 1u;
    unsigned hy0 = uy * 2654435761u;            // PRIMES[1], uint32 wraparound
    unsigned hy1 = (uy + 1u) * 2654435761u;
    unsigned hz0 = uz * 805459861u;             // PRIMES[2]
    unsigned hz1 = (uz + 1u) * 805459861u;

    // Corner order x-fastest: c&1 = x, (c>>1)&1 = y, (c>>2)&1 = z
    unsigned h[8] = {
        hx0 ^ hy0 ^ hz0,
        hx1 ^ hy0 ^ hz0,
        hx0 ^ hy1 ^ hz0,
        hx1 ^ hy1 ^ hz0,
        hx0 ^ hy0 ^ hz1,
        hx1 ^ hy0 ^ hz1,
        hx0 ^ hy1 ^ hz1,
        hx1 ^ hy1 ^ hz1,
    };

    unsigned slot[8];
    if (is_pow2) {
        unsigned mask = buckets - 1u;
        #pragma unroll
        for (int c = 0; c < 8; ++c) slot[c] = h[c] & mask;
    } else {
        #pragma unroll
        for (int c = 0; c < 8; ++c) slot[c] = h[c] % buckets;
    }

    // Issue all 16 float4 gathers before consuming any -> 16 loads in flight.
    float4 f0[8], f1[8];
    #pragma unroll
    for (int c = 0; c < 8; ++c) {
        const float4* fp = (const float4*)(feat + (size_t)slot[c] * 8u);
        f0[c] = fp[0];
        f1[c] = fp[1];
    }

    float wx0 = 1.0f - fx, wx1 = fx;
    float wy0 = 1.0f - fy, wy1 = fy;
    float wz0 = 1.0f - fz, wz1 = fz;
    // Same multiply order as reference: (wx*wy)*wz
    float w[8] = {
        (wx0 * wy0) * wz0, (wx1 * wy0) * wz0,
        (wx0 * wy1) * wz0, (wx1 * wy1) * wz0,
        (wx0 * wy0) * wz1, (wx1 * wy0) * wz1,
        (wx0 * wy1) * wz1, (wx1 * wy1) * wz1,
    };

    float4 a0 = make_float4(0.f, 0.f, 0.f, 0.f);
    float4 a1 = make_float4(0.f, 0.f, 0.f, 0.f);
    #pragma unroll
    for (int c = 0; c < 8; ++c) {   // summation order k = 0..7, matches einsum
        a0.x += w[c] * f0[c].x;
        a0.y += w[c] * f0[c].y;
        a0.z += w[c] * f0[c].z;
        a0.w += w[c] * f0[c].w;
        a1.x += w[c] * f1[c].x;
        a1.y += w[c] * f1[c].y;
        a1.z += w[c] * f1[c].z;
        a1.w += w[c] * f1[c].w;
    }

    float4* op = (float4*)(out + (size_t)i * 8u);
    op[0] = a0;
    op[1] = a1;
}

extern "C" void kernel_launch(void* const* d_in, const int* in_sizes, int n_in,
                              void* d_out, int out_size, void* d_ws, size_t ws_size,
                              hipStream_t stream) {
    const float* pts  = (const float*)d_in[0];
    const float* feat = (const float*)d_in[1];
    float* out = (float*)d_out;

    int N = in_sizes[0] / 3;
    unsigned buckets = (unsigned)(in_sizes[1] / 8);
    int is_pow2 = ((buckets & (buckets - 1u)) == 0u) ? 1 : 0;

    const int block = 256;
    const int grid = (N + block - 1) / block;
    hipLaunchKernelGGL(ngp_hash_interp, dim3(grid), dim3(block), 0, stream,
                       pts, feat, out, N, buckets, is_pow2);
}